// Round 3
// baseline (2172.363 us; speedup 1.0000x reference)
//
#include <hip/hip_runtime.h>

typedef __bf16 bf16_t;
typedef bf16_t bf16x8 __attribute__((ext_vector_type(8)));
typedef unsigned int u32x4 __attribute__((ext_vector_type(4)));
typedef float f32x4 __attribute__((ext_vector_type(4)));

typedef const __attribute__((address_space(1))) void* as1cv;
typedef __attribute__((address_space(3))) void* as3v;

#define DEVINL __device__ __forceinline__

constexpr int N_PTS = 65536;

DEVINL ushort f2bs(float x) {
  unsigned u = __builtin_bit_cast(unsigned, x);
  return (ushort)((u + 0x7fffu + ((u >> 16) & 1u)) >> 16);  // RNE
}
DEVINL float bs2f(ushort s) {
  unsigned u = ((unsigned)s) << 16;
  return __builtin_bit_cast(float, u);
}

// ---------------- prep: data f32 -> bf16 ----------------
__global__ __launch_bounds__(256) void cvt_data_k(const float* __restrict__ in,
                                                  ushort* __restrict__ out) {
  int i = (blockIdx.x * 256 + threadIdx.x) * 4;
  float4 v = *reinterpret_cast<const float4*>(in + i);
  ushort4 o;
  o.x = f2bs(v.x); o.y = f2bs(v.y); o.z = f2bs(v.z); o.w = f2bs(v.w);
  *reinterpret_cast<ushort4*>(out + i) = o;
}

// ---------------- prep: transpose weights to (N,K) bf16, ushort4 stores ----------------
__global__ __launch_bounds__(256) void prep_w_k(const float* __restrict__ Wqkv,
                                                const float* __restrict__ Wproj,
                                                ushort* __restrict__ WqkvT,
                                                ushort* __restrict__ WprojT) {
  int t = blockIdx.x * 256 + threadIdx.x;  // < 262144
  if (t < 196608) {                        // Wqkv: 128 k-groups x 1536 n
    int kg = t / 1536, n = t - kg * 1536;
    int k0 = kg * 4;
    ushort4 o;
    o.x = f2bs(Wqkv[(size_t)(k0 + 0) * 1536 + n]);
    o.y = f2bs(Wqkv[(size_t)(k0 + 1) * 1536 + n]);
    o.z = f2bs(Wqkv[(size_t)(k0 + 2) * 1536 + n]);
    o.w = f2bs(Wqkv[(size_t)(k0 + 3) * 1536 + n]);
    *reinterpret_cast<ushort4*>(&WqkvT[n * 512 + k0]) = o;
  } else {
    int t2 = t - 196608;                   // Wproj: 128 k-groups x 512 n
    int kg = t2 >> 9, n = t2 & 511;
    int k0 = kg * 4;
    ushort4 o;
    o.x = f2bs(Wproj[(size_t)(k0 + 0) * 512 + n]);
    o.y = f2bs(Wproj[(size_t)(k0 + 1) * 512 + n]);
    o.z = f2bs(Wproj[(size_t)(k0 + 2) * 512 + n]);
    o.w = f2bs(Wproj[(size_t)(k0 + 3) * 512 + n]);
    *reinterpret_cast<ushort4*>(&WprojT[n * 512 + k0]) = o;
  }
}

// ---------------- GEMM (B^T input), K=512, 128x128 tile ----------------
// - XCD-swizzled 1D grid (by-fastest) for A/B L2 reuse.
// - LDS K-chunk XOR swizzle key=(row>>1)&3, applied to BOTH the global source
//   address (global_load_lds dest is linear) and the fragment ds_read (rule #21).
// - ROPE epilogue: LDS transpose -> inline-asm global_store_dwordx4 (16B/lane;
//   compiler scalarized the C vector store into b16 stores -> 32x write amp).
// - ROPE output rows are permuted to window-major: m -> (g*4+dw)*24+ki.
template <int NC, bool ROPE>
__global__ __launch_bounds__(256) void gemm_bt_k(
    const ushort* __restrict__ A,    // M x 512 bf16
    const ushort* __restrict__ Bt,   // NC x 512 bf16
    const float* __restrict__ bias,  // NC
    const float* __restrict__ xyz,   // N x 3 (ROPE only)
    const float* __restrict__ freqs, // 8 x 32 x 3 (ROPE only)
    ushort* __restrict__ Obf,        // bf16 out, window-major rows (ROPE)
    float* __restrict__ Of)          // f32 out (!ROPE)
{
  __shared__ alignas(16) ushort sA[128 * 32];
  __shared__ alignas(16) ushort sB[128 * 32];
  const int tid  = threadIdx.x;
  const int lane = tid & 63;
  const int w    = tid >> 6;
  const int wm = w >> 1, wn = w & 1;

  constexpr int NBY = NC / 128;
  const int cpx = (int)gridDim.x >> 3;
  const int bid = (int)blockIdx.x;
  const int wid = (bid & 7) * cpx + (bid >> 3);
  const int bxi = wid / NBY;
  const int byi = wid - bxi * NBY;
  const int tileM = bxi * 128;
  const int tileN = byi * 128;

  f32x4 acc[4][4] = {};

  const int r0 = tid >> 2;
  // pre-swizzled global source chunk (LDS dest stays linear)
  const int kb = (((tid & 3) ^ ((r0 >> 1) & 3)) << 3);
  const ushort* gA0 = A  + (size_t)(tileM + r0) * 512 + kb;
  const ushort* gB0 = Bt + (size_t)(tileN + r0) * 512 + kb;
  const ushort* gA1 = A  + (size_t)(tileM + r0 + 64) * 512 + kb;
  const ushort* gB1 = Bt + (size_t)(tileN + r0 + 64) * 512 + kb;
  ushort* lA0 = &sA[(w * 64) * 8];
  ushort* lB0 = &sB[(w * 64) * 8];
  ushort* lA1 = &sA[(256 + w * 64) * 8];
  ushort* lB1 = &sB[(256 + w * 64) * 8];

  const int krow = (lane >> 4) * 8;
  const int swz  = ((lane & 15) >> 1) & 3;   // == (row>>1)&3 for fragment rows

  for (int k0 = 0; k0 < 512; k0 += 32) {
    __builtin_amdgcn_global_load_lds((as1cv)(gA0 + k0), (as3v)lA0, 16, 0, 0);
    __builtin_amdgcn_global_load_lds((as1cv)(gB0 + k0), (as3v)lB0, 16, 0, 0);
    __builtin_amdgcn_global_load_lds((as1cv)(gA1 + k0), (as3v)lA1, 16, 0, 0);
    __builtin_amdgcn_global_load_lds((as1cv)(gB1 + k0), (as3v)lB1, 16, 0, 0);
    __syncthreads();

    bf16x8 af[4], bfr[4];
#pragma unroll
    for (int i = 0; i < 4; ++i) {
      const int rA = wm * 64 + i * 16 + (lane & 15);
      const int rB = wn * 64 + i * 16 + (lane & 15);
      af[i]  = *reinterpret_cast<const bf16x8*>(&sA[rA * 32 + (krow ^ (swz << 3))]);
      bfr[i] = *reinterpret_cast<const bf16x8*>(&sB[rB * 32 + (krow ^ (swz << 3))]);
    }
#pragma unroll
    for (int i = 0; i < 4; ++i)
#pragma unroll
      for (int j = 0; j < 4; ++j)
        acc[i][j] = __builtin_amdgcn_mfma_f32_16x16x32_bf16(af[i], bfr[j], acc[i][j], 0, 0, 0);
    __syncthreads();
  }

  // epilogue: C frag layout col = lane&15, row = (lane>>4)*4 + reg
  const int cl   = lane & 15;
  const int rb   = (lane >> 4) * 4;
  const int wrow = tileM + wm * 64;
  const int wcol = tileN + wn * 64;
  float bsv[4];
#pragma unroll
  for (int nf = 0; nf < 4; ++nf) bsv[nf] = bias[wcol + nf * 16 + cl];

  if constexpr (ROPE) {
    __shared__ alignas(16) ushort stg[4][16 * 64];
    const int which = wcol >> 9;
    const int h = (wcol >> 6) & 7;
    const float* fp0 = freqs + (h * 32 + cl) * 3;
    const float* fp1 = freqs + (h * 32 + 16 + cl) * 3;
    const float f00 = fp0[0], f01 = fp0[1], f02 = fp0[2];
    const float f10 = fp1[0], f11 = fp1[1], f12 = fp1[2];
    ushort* swg = stg[w];
#pragma unroll
    for (int mf = 0; mf < 4; ++mf) {
      // ---- write phase: swizzled b16 writes into per-wave staging ----
#pragma unroll
      for (int r = 0; r < 4; ++r) {
        const int row = rb + r;             // local row 0..15
        const int m = wrow + mf * 16 + row;
        const int sx = (row & 7) << 3;      // ushort-index XOR swizzle
        ushort* sr = &swg[row * 64];
        if (which < 2) {
          const float x0 = xyz[3 * m + 0], x1 = xyz[3 * m + 1], x2 = xyz[3 * m + 2];
          const float th0 = x0 * f00 + x1 * f01 + x2 * f02;
          const float th1 = x0 * f10 + x1 * f11 + x2 * f12;
          const float s0 = sinf(th0), c0 = cosf(th0);
          const float s1 = sinf(th1), c1 = cosf(th1);
          const float v0 = acc[mf][0][r] + bsv[0];
          const float v1 = acc[mf][1][r] + bsv[1];
          const float v2 = acc[mf][2][r] + bsv[2];
          const float v3 = acc[mf][3][r] + bsv[3];
          sr[(cl)      ^ sx] = f2bs(v0 * c0 - v2 * s0);
          sr[(16 + cl) ^ sx] = f2bs(v1 * c1 - v3 * s1);
          sr[(32 + cl) ^ sx] = f2bs(v0 * s0 + v2 * c0);
          sr[(48 + cl) ^ sx] = f2bs(v1 * s1 + v3 * c1);
        } else {  // v: no rope
#pragma unroll
          for (int nf = 0; nf < 4; ++nf)
            sr[(nf * 16 + cl) ^ sx] = f2bs(acc[mf][nf][r] + bsv[nf]);
        }
      }
      asm volatile("s_waitcnt lgkmcnt(0)" ::: "memory");
      __builtin_amdgcn_sched_barrier(0);
      // ---- read phase: ds_read_b128 -> inline-asm global_store_dwordx4 ----
      {
        const int lrow = lane >> 2;                 // 0..15
        const int m = wrow + mf * 16 + lrow;
        const int a = m + 12;
        const int g96 = a / 96;
        const int rr = a - g96 * 96;
        const int orow = (g96 * 4 + (rr & 3)) * 24 + (rr >> 2);  // window-major row
#pragma unroll
        for (int inst = 0; inst < 2; ++inst) {
          const int chunk = (lane & 3) + inst * 4;  // 8-ushort group 0..7
          u32x4 v = *reinterpret_cast<const u32x4*>(
              &swg[lrow * 64 + ((chunk ^ (lrow & 7)) << 3)]);
          const ushort* p = Obf + (size_t)orow * NC + wcol + chunk * 8;
          asm volatile("global_store_dwordx4 %0, %1, off" :: "v"(p), "v"(v) : "memory");
        }
      }
      __builtin_amdgcn_sched_barrier(0);
    }
  } else {
    // f32 output: 16-lane x 4B contiguous segments coalesce fine
#pragma unroll
    for (int mf = 0; mf < 4; ++mf)
#pragma unroll
      for (int r = 0; r < 4; ++r) {
        const int m = wrow + mf * 16 + rb + r;
        float* orow = Of + (size_t)m * NC + wcol;
#pragma unroll
        for (int nf = 0; nf < 4; ++nf) orow[nf * 16 + cl] = acc[mf][nf][r] + bsv[nf];
      }
  }
}

// ---------------- windowed attention: one wave per (window b, head h) ----------------
// qkv is window-major: row b*24+ki holds point n = g*96+dw+4*ki-12 (b=g*4+dw)
__global__ __launch_bounds__(64) void attn_win_k(const ushort* __restrict__ qkv,  // [65568][1536] bf16
                                                 const float* __restrict__ mask,  // B x 24 x 24
                                                 ushort* __restrict__ outa)       // N x 512 bf16 (point-major)
{
  __shared__ float sq[24][68];
  __shared__ float sk[24][68];
  __shared__ float sv[24][68];
  __shared__ float sS[24][25];
  const int bid = blockIdx.x;
  const int b = bid >> 3, h = bid & 7;
  const int g = b >> 2, dw = b & 3;
  const int lane  = threadIdx.x;
  const int nbase = g * 96 + dw - 12;  // + ki*4

  for (int ki = 0; ki < 24; ++ki) {
    int n = nbase + ki * 4;
    float q, k, v;
    if (n < 0) { q = k = v = -1.0f; }                 // head pad rows are -1.0
    else if (n >= N_PTS) { q = k = v = 0.0f; }        // tail pad rows are 0
    else {
      const ushort* p = qkv + (size_t)(b * 24 + ki) * 1536 + h * 64 + lane;
      q = bs2f(p[0]); k = bs2f(p[512]); v = bs2f(p[1024]);
    }
    sq[ki][lane] = q; sk[ki][lane] = k; sv[ki][lane] = v;
  }
  __syncthreads();

  for (int j = 0; j < 9; ++j) {
    int e = j * 64 + lane;
    int qi = e / 24, ki = e - qi * 24;
    float s = 0.f;
#pragma unroll
    for (int d = 0; d < 64; ++d) s = fmaf(sq[qi][d], sk[ki][d], s);
    sS[qi][ki] = s * 0.125f + mask[(size_t)b * 576 + e];
  }
  __syncthreads();

  if (lane < 24) {
    float mx = -3.4e38f;
#pragma unroll
    for (int k2 = 0; k2 < 24; ++k2) mx = fmaxf(mx, sS[lane][k2]);
    float sum = 0.f;
#pragma unroll
    for (int k2 = 0; k2 < 24; ++k2) { float t = expf(sS[lane][k2] - mx); sum += t; sS[lane][k2] = t; }
    float inv = 1.0f / sum;
#pragma unroll
    for (int k2 = 0; k2 < 24; ++k2) sS[lane][k2] *= inv;
  }
  __syncthreads();

  for (int qi = 0; qi < 24; ++qi) {
    int n = nbase + qi * 4;
    if (n < 0 || n >= N_PTS) continue;
    float o = 0.f;
#pragma unroll
    for (int ki = 0; ki < 24; ++ki) o = fmaf(sS[qi][ki], sv[ki][lane], o);
    outa[(size_t)n * 512 + h * 64 + lane] = f2bs(o);
  }
}

extern "C" void kernel_launch(void* const* d_in, const int* in_sizes, int n_in,
                              void* d_out, int out_size, void* d_ws, size_t ws_size,
                              hipStream_t stream) {
  const float* data  = (const float*)d_in[0];
  const float* xyz   = (const float*)d_in[1];
  const float* mask  = (const float*)d_in[2];
  const float* Wqkv  = (const float*)d_in[3];
  const float* bqkv  = (const float*)d_in[4];
  const float* Wproj = (const float*)d_in[5];
  const float* bproj = (const float*)d_in[6];
  const float* freqs = (const float*)d_in[7];
  float* out = (float*)d_out;

  char* ws = (char*)d_ws;
  // layout: qkv window-major 65568 rows x 1536 bf16 (201.4MB) | dat_bf / attn-out (64MB)
  //         | WqkvT (1.5MB) | WprojT (0.5MB)
  ushort* qkv_ws = (ushort*)ws;
  ushort* dat_bf = (ushort*)(ws + (size_t)201424896);
  ushort* WqkvT  = (ushort*)(ws + (size_t)268533760);
  ushort* WprojT = (ushort*)(ws + (size_t)270106624);

  cvt_data_k<<<32768, 256, 0, stream>>>(data, dat_bf);
  prep_w_k<<<1024, 256, 0, stream>>>(Wqkv, Wproj, WqkvT, WprojT);
  gemm_bt_k<1536, true><<<6144, 256, 0, stream>>>(dat_bf, WqkvT, bqkv, xyz, freqs, qkv_ws, nullptr);
  attn_win_k<<<21856, 64, 0, stream>>>(qkv_ws, mask, dat_bf);
  gemm_bt_k<512, false><<<2048, 256, 0, stream>>>(dat_bf, WprojT, bproj, nullptr, nullptr, nullptr, out);
}

// Round 4
// 2142.147 us; speedup vs baseline: 1.0141x; 1.0141x over previous
//
#include <hip/hip_runtime.h>

typedef __bf16 bf16_t;
typedef bf16_t bf16x8 __attribute__((ext_vector_type(8)));
typedef unsigned int u32x4 __attribute__((ext_vector_type(4)));
typedef float f32x4 __attribute__((ext_vector_type(4)));

#define DEVINL __device__ __forceinline__

constexpr int N_PTS = 65536;

DEVINL ushort f2bs(float x) {
  unsigned u = __builtin_bit_cast(unsigned, x);
  return (ushort)((u + 0x7fffu + ((u >> 16) & 1u)) >> 16);  // RNE
}
DEVINL float bs2f(ushort s) {
  unsigned u = ((unsigned)s) << 16;
  return __builtin_bit_cast(float, u);
}

// ---------------- prep: data f32 -> bf16 ----------------
__global__ __launch_bounds__(256) void cvt_data_k(const float* __restrict__ in,
                                                  ushort* __restrict__ out) {
  int i = (blockIdx.x * 256 + threadIdx.x) * 4;
  float4 v = *reinterpret_cast<const float4*>(in + i);
  ushort4 o;
  o.x = f2bs(v.x); o.y = f2bs(v.y); o.z = f2bs(v.z); o.w = f2bs(v.w);
  *reinterpret_cast<ushort4*>(out + i) = o;
}

// ---------------- prep: transpose weights to (N,K) bf16 ----------------
__global__ __launch_bounds__(256) void prep_w_k(const float* __restrict__ Wqkv,
                                                const float* __restrict__ Wproj,
                                                ushort* __restrict__ WqkvT,
                                                ushort* __restrict__ WprojT) {
  int t = blockIdx.x * 256 + threadIdx.x;  // < 262144
  if (t < 196608) {                        // Wqkv: 128 k-groups x 1536 n
    int kg = t / 1536, n = t - kg * 1536;
    int k0 = kg * 4;
    ushort4 o;
    o.x = f2bs(Wqkv[(size_t)(k0 + 0) * 1536 + n]);
    o.y = f2bs(Wqkv[(size_t)(k0 + 1) * 1536 + n]);
    o.z = f2bs(Wqkv[(size_t)(k0 + 2) * 1536 + n]);
    o.w = f2bs(Wqkv[(size_t)(k0 + 3) * 1536 + n]);
    *reinterpret_cast<ushort4*>(&WqkvT[n * 512 + k0]) = o;
  } else {
    int t2 = t - 196608;                   // Wproj: 128 k-groups x 512 n
    int kg = t2 >> 9, n = t2 & 511;
    int k0 = kg * 4;
    ushort4 o;
    o.x = f2bs(Wproj[(size_t)(k0 + 0) * 512 + n]);
    o.y = f2bs(Wproj[(size_t)(k0 + 1) * 512 + n]);
    o.z = f2bs(Wproj[(size_t)(k0 + 2) * 512 + n]);
    o.w = f2bs(Wproj[(size_t)(k0 + 3) * 512 + n]);
    *reinterpret_cast<ushort4*>(&WprojT[n * 512 + k0]) = o;
  }
}

// ---------------- GEMM (B^T input), K=512, 128x128 tile, reg-staged dbuf ----------------
// global_load_lds on this chip/ROCm issues 64B write-class TCC requests per lane-op
// (measured: WRITE_SIZE == 64B x #gload_lds, R1-R3 invariant) and bypasses L2
// allocation (FETCH == pure streaming). So: reg-stage global->VGPR->ds_write_b128,
// double-buffered, one barrier/iter, next-tile loads issued before current MFMAs.
// LDS k-chunk XOR swizzle key=(row>>1)&3 on BOTH ds_write and ds_read (involution).
template <int NC, bool ROPE>
__global__ __launch_bounds__(256) void gemm_bt_k(
    const ushort* __restrict__ A,    // M x 512 bf16
    const ushort* __restrict__ Bt,   // NC x 512 bf16
    const float* __restrict__ bias,  // NC
    const float* __restrict__ xyz,   // N x 3 (ROPE only)
    const float* __restrict__ freqs, // 8 x 32 x 3 (ROPE only)
    ushort* __restrict__ Obf,        // bf16 out, window-major rows (ROPE)
    float* __restrict__ Of)          // f32 out (!ROPE)
{
  __shared__ alignas(16) ushort sA[2][128 * 32];
  __shared__ alignas(16) ushort sB[2][128 * 32];
  const int tid  = threadIdx.x;
  const int lane = tid & 63;
  const int w    = tid >> 6;
  const int wm = w >> 1, wn = w & 1;

  constexpr int NBY = NC / 128;
  const int cpx = (int)gridDim.x >> 3;
  const int bid = (int)blockIdx.x;
  const int wid = (bid & 7) * cpx + (bid >> 3);
  const int bxi = wid / NBY;
  const int byi = wid - bxi * NBY;
  const int tileM = bxi * 128;
  const int tileN = byi * 128;

  f32x4 acc[4][4] = {};

  const int r0 = tid >> 2;   // 0..63
  const int c0 = tid & 3;    // k-chunk of 8 bf16
  const ushort* gA0 = A  + (size_t)(tileM + r0) * 512 + c0 * 8;
  const ushort* gB0 = Bt + (size_t)(tileN + r0) * 512 + c0 * 8;
  const ushort* gA1 = gA0 + 64 * 512;
  const ushort* gB1 = gB0 + 64 * 512;
  const int key = (r0 >> 1) & 3;               // same for r0 and r0+64
  const int xw0 = r0 * 32 + ((c0 ^ key) << 3);
  const int xw1 = (r0 + 64) * 32 + ((c0 ^ key) << 3);

  const int krow = (lane >> 4) * 8;
  const int swz8 = (((lane & 15) >> 1) & 3) << 3;

  // prologue: tile 0
  u32x4 pA0 = *reinterpret_cast<const u32x4*>(gA0);
  u32x4 pB0 = *reinterpret_cast<const u32x4*>(gB0);
  u32x4 pA1 = *reinterpret_cast<const u32x4*>(gA1);
  u32x4 pB1 = *reinterpret_cast<const u32x4*>(gB1);
  *reinterpret_cast<u32x4*>(&sA[0][xw0]) = pA0;
  *reinterpret_cast<u32x4*>(&sB[0][xw0]) = pB0;
  *reinterpret_cast<u32x4*>(&sA[0][xw1]) = pA1;
  *reinterpret_cast<u32x4*>(&sB[0][xw1]) = pB1;
  __syncthreads();

  int cur = 0;
#pragma unroll 1
  for (int t = 0; t < 16; ++t) {
    u32x4 nA0, nB0, nA1, nB1;
    if (t < 15) {
      const int k0 = (t + 1) * 32;
      nA0 = *reinterpret_cast<const u32x4*>(gA0 + k0);
      nB0 = *reinterpret_cast<const u32x4*>(gB0 + k0);
      nA1 = *reinterpret_cast<const u32x4*>(gA1 + k0);
      nB1 = *reinterpret_cast<const u32x4*>(gB1 + k0);
    }

    bf16x8 af[4], bfr[4];
#pragma unroll
    for (int i = 0; i < 4; ++i) {
      const int rA = wm * 64 + i * 16 + (lane & 15);
      const int rB = wn * 64 + i * 16 + (lane & 15);
      af[i]  = *reinterpret_cast<const bf16x8*>(&sA[cur][rA * 32 + (krow ^ swz8)]);
      bfr[i] = *reinterpret_cast<const bf16x8*>(&sB[cur][rB * 32 + (krow ^ swz8)]);
    }
#pragma unroll
    for (int i = 0; i < 4; ++i)
#pragma unroll
      for (int j = 0; j < 4; ++j)
        acc[i][j] = __builtin_amdgcn_mfma_f32_16x16x32_bf16(af[i], bfr[j], acc[i][j], 0, 0, 0);

    if (t < 15) {
      const int nxt = cur ^ 1;
      *reinterpret_cast<u32x4*>(&sA[nxt][xw0]) = nA0;
      *reinterpret_cast<u32x4*>(&sB[nxt][xw0]) = nB0;
      *reinterpret_cast<u32x4*>(&sA[nxt][xw1]) = nA1;
      *reinterpret_cast<u32x4*>(&sB[nxt][xw1]) = nB1;
      __syncthreads();
      cur = nxt;
    }
  }

  // epilogue: C frag layout col = lane&15, row = (lane>>4)*4 + reg. Direct stores
  // (b16 store write-traffic measured to be ~3% of total in R1 — not the issue).
  const int cl   = lane & 15;
  const int rb   = (lane >> 4) * 4;
  const int wrow = tileM + wm * 64;
  const int wcol = tileN + wn * 64;
  float bsv[4];
#pragma unroll
  for (int nf = 0; nf < 4; ++nf) bsv[nf] = bias[wcol + nf * 16 + cl];

  if constexpr (ROPE) {
    const int which = wcol >> 9;
    const int h = (wcol >> 6) & 7;
    const float* fp0 = freqs + (h * 32 + cl) * 3;
    const float* fp1 = freqs + (h * 32 + 16 + cl) * 3;
    const float f00 = fp0[0], f01 = fp0[1], f02 = fp0[2];
    const float f10 = fp1[0], f11 = fp1[1], f12 = fp1[2];
#pragma unroll
    for (int mf = 0; mf < 4; ++mf) {
#pragma unroll
      for (int r = 0; r < 4; ++r) {
        const int m = wrow + mf * 16 + rb + r;
        const int a = m + 12;
        const int g96 = a / 96;
        const int rr = a - g96 * 96;
        const int orow = (g96 * 4 + (rr & 3)) * 24 + (rr >> 2);  // window-major row
        ushort* op = Obf + (size_t)orow * NC + wcol;
        if (which < 2) {
          const float x0 = xyz[3 * m + 0], x1 = xyz[3 * m + 1], x2 = xyz[3 * m + 2];
          const float th0 = x0 * f00 + x1 * f01 + x2 * f02;
          const float th1 = x0 * f10 + x1 * f11 + x2 * f12;
          const float s0 = sinf(th0), c0 = cosf(th0);
          const float s1 = sinf(th1), c1 = cosf(th1);
          const float v0 = acc[mf][0][r] + bsv[0];
          const float v1 = acc[mf][1][r] + bsv[1];
          const float v2 = acc[mf][2][r] + bsv[2];
          const float v3 = acc[mf][3][r] + bsv[3];
          op[cl]      = f2bs(v0 * c0 - v2 * s0);
          op[16 + cl] = f2bs(v1 * c1 - v3 * s1);
          op[32 + cl] = f2bs(v0 * s0 + v2 * c0);
          op[48 + cl] = f2bs(v1 * s1 + v3 * c1);
        } else {  // v: no rope
#pragma unroll
          for (int nf = 0; nf < 4; ++nf) op[nf * 16 + cl] = f2bs(acc[mf][nf][r] + bsv[nf]);
        }
      }
    }
  } else {
#pragma unroll
    for (int mf = 0; mf < 4; ++mf)
#pragma unroll
      for (int r = 0; r < 4; ++r) {
        const int m = wrow + mf * 16 + rb + r;
        float* orow = Of + (size_t)m * NC + wcol;
#pragma unroll
        for (int nf = 0; nf < 4; ++nf) orow[nf * 16 + cl] = acc[mf][nf][r] + bsv[nf];
      }
  }
}

// ---------------- windowed attention: one wave per (window b, head h) ----------------
// qkv is window-major: row b*24+ki holds point n = g*96+dw+4*ki-12 (b=g*4+dw)
__global__ __launch_bounds__(64) void attn_win_k(const ushort* __restrict__ qkv,  // [65568][1536] bf16
                                                 const float* __restrict__ mask,  // B x 24 x 24
                                                 ushort* __restrict__ outa)       // N x 512 bf16 (point-major)
{
  __shared__ float sq[24][68];
  __shared__ float sk[24][68];
  __shared__ float sv[24][68];
  __shared__ float sS[24][25];
  const int bid = blockIdx.x;
  const int b = bid >> 3, h = bid & 7;
  const int g = b >> 2, dw = b & 3;
  const int lane  = threadIdx.x;
  const int nbase = g * 96 + dw - 12;  // + ki*4

  for (int ki = 0; ki < 24; ++ki) {
    int n = nbase + ki * 4;
    float q, k, v;
    if (n < 0) { q = k = v = -1.0f; }                 // head pad rows are -1.0
    else if (n >= N_PTS) { q = k = v = 0.0f; }        // tail pad rows are 0
    else {
      const ushort* p = qkv + (size_t)(b * 24 + ki) * 1536 + h * 64 + lane;
      q = bs2f(p[0]); k = bs2f(p[512]); v = bs2f(p[1024]);
    }
    sq[ki][lane] = q; sk[ki][lane] = k; sv[ki][lane] = v;
  }
  __syncthreads();

  for (int j = 0; j < 9; ++j) {
    int e = j * 64 + lane;
    int qi = e / 24, ki = e - qi * 24;
    float s = 0.f;
#pragma unroll
    for (int d = 0; d < 64; ++d) s = fmaf(sq[qi][d], sk[ki][d], s);
    sS[qi][ki] = s * 0.125f + mask[(size_t)b * 576 + e];
  }
  __syncthreads();

  if (lane < 24) {
    float mx = -3.4e38f;
#pragma unroll
    for (int k2 = 0; k2 < 24; ++k2) mx = fmaxf(mx, sS[lane][k2]);
    float sum = 0.f;
#pragma unroll
    for (int k2 = 0; k2 < 24; ++k2) { float t = expf(sS[lane][k2] - mx); sum += t; sS[lane][k2] = t; }
    float inv = 1.0f / sum;
#pragma unroll
    for (int k2 = 0; k2 < 24; ++k2) sS[lane][k2] *= inv;
  }
  __syncthreads();

  for (int qi = 0; qi < 24; ++qi) {
    int n = nbase + qi * 4;
    if (n < 0 || n >= N_PTS) continue;
    float o = 0.f;
#pragma unroll
    for (int ki = 0; ki < 24; ++ki) o = fmaf(sS[qi][ki], sv[ki][lane], o);
    outa[(size_t)n * 512 + h * 64 + lane] = f2bs(o);
  }
}

extern "C" void kernel_launch(void* const* d_in, const int* in_sizes, int n_in,
                              void* d_out, int out_size, void* d_ws, size_t ws_size,
                              hipStream_t stream) {
  const float* data  = (const float*)d_in[0];
  const float* xyz   = (const float*)d_in[1];
  const float* mask  = (const float*)d_in[2];
  const float* Wqkv  = (const float*)d_in[3];
  const float* bqkv  = (const float*)d_in[4];
  const float* Wproj = (const float*)d_in[5];
  const float* bproj = (const float*)d_in[6];
  const float* freqs = (const float*)d_in[7];
  float* out = (float*)d_out;

  char* ws = (char*)d_ws;
  // layout: qkv window-major 65568 rows x 1536 bf16 (201.4MB) | dat_bf / attn-out (64MB)
  //         | WqkvT (1.5MB) | WprojT (0.5MB)
  ushort* qkv_ws = (ushort*)ws;
  ushort* dat_bf = (ushort*)(ws + (size_t)201424896);
  ushort* WqkvT  = (ushort*)(ws + (size_t)268533760);
  ushort* WprojT = (ushort*)(ws + (size_t)270106624);

  cvt_data_k<<<32768, 256, 0, stream>>>(data, dat_bf);
  prep_w_k<<<1024, 256, 0, stream>>>(Wqkv, Wproj, WqkvT, WprojT);
  gemm_bt_k<1536, true><<<6144, 256, 0, stream>>>(dat_bf, WqkvT, bqkv, xyz, freqs, qkv_ws, nullptr);
  attn_win_k<<<21856, 64, 0, stream>>>(qkv_ws, mask, dat_bf);
  gemm_bt_k<512, false><<<2048, 256, 0, stream>>>(dat_bf, WprojT, bproj, nullptr, nullptr, nullptr, out);
}

// Round 5
// 2130.367 us; speedup vs baseline: 1.0197x; 1.0055x over previous
//
#include <hip/hip_runtime.h>

typedef __bf16 bf16_t;
typedef bf16_t bf16x8 __attribute__((ext_vector_type(8)));
typedef unsigned int u32x4 __attribute__((ext_vector_type(4)));
typedef float f32x4 __attribute__((ext_vector_type(4)));

#define DEVINL __device__ __forceinline__

constexpr int N_PTS = 65536;

DEVINL ushort f2bs(float x) {
  unsigned u = __builtin_bit_cast(unsigned, x);
  return (ushort)((u + 0x7fffu + ((u >> 16) & 1u)) >> 16);  // RNE
}
DEVINL float bs2f(ushort s) {
  unsigned u = ((unsigned)s) << 16;
  return __builtin_bit_cast(float, u);
}

// ---------------- prep: data f32 -> bf16 ----------------
__global__ __launch_bounds__(256) void cvt_data_k(const float* __restrict__ in,
                                                  ushort* __restrict__ out) {
  int i = (blockIdx.x * 256 + threadIdx.x) * 4;
  float4 v = *reinterpret_cast<const float4*>(in + i);
  ushort4 o;
  o.x = f2bs(v.x); o.y = f2bs(v.y); o.z = f2bs(v.z); o.w = f2bs(v.w);
  *reinterpret_cast<ushort4*>(out + i) = o;
}

// ---------------- prep: transpose weights to (N,K) bf16 ----------------
__global__ __launch_bounds__(256) void prep_w_k(const float* __restrict__ Wqkv,
                                                const float* __restrict__ Wproj,
                                                ushort* __restrict__ WqkvT,
                                                ushort* __restrict__ WprojT) {
  int t = blockIdx.x * 256 + threadIdx.x;  // < 262144
  if (t < 196608) {                        // Wqkv: 128 k-groups x 1536 n
    int kg = t / 1536, n = t - kg * 1536;
    int k0 = kg * 4;
    ushort4 o;
    o.x = f2bs(Wqkv[(size_t)(k0 + 0) * 1536 + n]);
    o.y = f2bs(Wqkv[(size_t)(k0 + 1) * 1536 + n]);
    o.z = f2bs(Wqkv[(size_t)(k0 + 2) * 1536 + n]);
    o.w = f2bs(Wqkv[(size_t)(k0 + 3) * 1536 + n]);
    *reinterpret_cast<ushort4*>(&WqkvT[n * 512 + k0]) = o;
  } else {
    int t2 = t - 196608;                   // Wproj: 128 k-groups x 512 n
    int kg = t2 >> 9, n = t2 & 511;
    int k0 = kg * 4;
    ushort4 o;
    o.x = f2bs(Wproj[(size_t)(k0 + 0) * 512 + n]);
    o.y = f2bs(Wproj[(size_t)(k0 + 1) * 512 + n]);
    o.z = f2bs(Wproj[(size_t)(k0 + 2) * 512 + n]);
    o.w = f2bs(Wproj[(size_t)(k0 + 3) * 512 + n]);
    *reinterpret_cast<ushort4*>(&WprojT[n * 512 + k0]) = o;
  }
}

// ---------------- GEMM (B^T input), K=512, 128x128 tile, reg-staged dbuf ----------------
// TCC write-traffic laws measured R1-R4 on this chip:
//   (a) global_load_lds issues a 64B write-class TCC request PER LANE-OP  -> never use it here
//   (b) sub-dword (b16) stores get zero inter-lane merging: 64B line PER LANE-OP
// So: main loop reg-stages global->VGPR->ds_write_b128 (dbuf, 1 barrier/iter);
// bf16 epilogue transposes through per-wave LDS and stores via inline-asm
// global_store_dwordx4 (16B/lane, full lines). f32 (dword) stores coalesce fine.
template <int NC, bool ROPE>
__global__ __launch_bounds__(256) void gemm_bt_k(
    const ushort* __restrict__ A,    // M x 512 bf16
    const ushort* __restrict__ Bt,   // NC x 512 bf16
    const float* __restrict__ bias,  // NC
    const float* __restrict__ xyz,   // N x 3 (ROPE only)
    const float* __restrict__ freqs, // 8 x 32 x 3 (ROPE only)
    ushort* __restrict__ Obf,        // bf16 out, window-major rows (ROPE)
    float* __restrict__ Of)          // f32 out (!ROPE)
{
  __shared__ alignas(16) ushort sA[2][128 * 32];
  __shared__ alignas(16) ushort sB[2][128 * 32];
  const int tid  = threadIdx.x;
  const int lane = tid & 63;
  const int w    = tid >> 6;
  const int wm = w >> 1, wn = w & 1;

  constexpr int NBY = NC / 128;
  const int cpx = (int)gridDim.x >> 3;
  const int bid = (int)blockIdx.x;
  const int wid = (bid & 7) * cpx + (bid >> 3);
  const int bxi = wid / NBY;
  const int byi = wid - bxi * NBY;
  const int tileM = bxi * 128;
  const int tileN = byi * 128;

  f32x4 acc[4][4] = {};

  const int r0 = tid >> 2;   // 0..63
  const int c0 = tid & 3;    // k-chunk of 8 bf16
  const ushort* gA0 = A  + (size_t)(tileM + r0) * 512 + c0 * 8;
  const ushort* gB0 = Bt + (size_t)(tileN + r0) * 512 + c0 * 8;
  const ushort* gA1 = gA0 + 64 * 512;
  const ushort* gB1 = gB0 + 64 * 512;
  const int key = (r0 >> 1) & 3;               // same for r0 and r0+64
  const int xw0 = r0 * 32 + ((c0 ^ key) << 3);
  const int xw1 = (r0 + 64) * 32 + ((c0 ^ key) << 3);

  const int krow = (lane >> 4) * 8;
  const int swz8 = (((lane & 15) >> 1) & 3) << 3;

  // prologue: tile 0
  u32x4 pA0 = *reinterpret_cast<const u32x4*>(gA0);
  u32x4 pB0 = *reinterpret_cast<const u32x4*>(gB0);
  u32x4 pA1 = *reinterpret_cast<const u32x4*>(gA1);
  u32x4 pB1 = *reinterpret_cast<const u32x4*>(gB1);
  *reinterpret_cast<u32x4*>(&sA[0][xw0]) = pA0;
  *reinterpret_cast<u32x4*>(&sB[0][xw0]) = pB0;
  *reinterpret_cast<u32x4*>(&sA[0][xw1]) = pA1;
  *reinterpret_cast<u32x4*>(&sB[0][xw1]) = pB1;
  __syncthreads();

  int cur = 0;
#pragma unroll 1
  for (int t = 0; t < 16; ++t) {
    u32x4 nA0, nB0, nA1, nB1;
    if (t < 15) {
      const int k0 = (t + 1) * 32;
      nA0 = *reinterpret_cast<const u32x4*>(gA0 + k0);
      nB0 = *reinterpret_cast<const u32x4*>(gB0 + k0);
      nA1 = *reinterpret_cast<const u32x4*>(gA1 + k0);
      nB1 = *reinterpret_cast<const u32x4*>(gB1 + k0);
    }

    bf16x8 af[4], bfr[4];
#pragma unroll
    for (int i = 0; i < 4; ++i) {
      const int rA = wm * 64 + i * 16 + (lane & 15);
      const int rB = wn * 64 + i * 16 + (lane & 15);
      af[i]  = *reinterpret_cast<const bf16x8*>(&sA[cur][rA * 32 + (krow ^ swz8)]);
      bfr[i] = *reinterpret_cast<const bf16x8*>(&sB[cur][rB * 32 + (krow ^ swz8)]);
    }
#pragma unroll
    for (int i = 0; i < 4; ++i)
#pragma unroll
      for (int j = 0; j < 4; ++j)
        acc[i][j] = __builtin_amdgcn_mfma_f32_16x16x32_bf16(af[i], bfr[j], acc[i][j], 0, 0, 0);

    if (t < 15) {
      const int nxt = cur ^ 1;
      *reinterpret_cast<u32x4*>(&sA[nxt][xw0]) = nA0;
      *reinterpret_cast<u32x4*>(&sB[nxt][xw0]) = nB0;
      *reinterpret_cast<u32x4*>(&sA[nxt][xw1]) = nA1;
      *reinterpret_cast<u32x4*>(&sB[nxt][xw1]) = nB1;
      __syncthreads();
      cur = nxt;
    }
  }

  // epilogue: C frag layout col = lane&15, row = (lane>>4)*4 + reg
  const int cl   = lane & 15;
  const int rb   = (lane >> 4) * 4;
  const int wrow = tileM + wm * 64;
  const int wcol = tileN + wn * 64;
  float bsv[4];
#pragma unroll
  for (int nf = 0; nf < 4; ++nf) bsv[nf] = bias[wcol + nf * 16 + cl];

  if constexpr (ROPE) {
    // per-wave staging aliased onto sA[0] (free after the t=14 barrier; sA[0] is
    // only read at t<=14, final iter reads buffer 1; each wave touches only its
    // own quarter, so no inter-wave hazard).
    ushort* swg = &sA[0][w * 1024];
    const int which = wcol >> 9;
    const int h = (wcol >> 6) & 7;
    const float* fp0 = freqs + (h * 32 + cl) * 3;
    const float* fp1 = freqs + (h * 32 + 16 + cl) * 3;
    const float f00 = fp0[0], f01 = fp0[1], f02 = fp0[2];
    const float f10 = fp1[0], f11 = fp1[1], f12 = fp1[2];
#pragma unroll
    for (int mf = 0; mf < 4; ++mf) {
      // ---- write phase: swizzled b16 writes into per-wave staging ----
#pragma unroll
      for (int r = 0; r < 4; ++r) {
        const int row = rb + r;             // local row 0..15
        const int m = wrow + mf * 16 + row;
        const int sx = (row & 7) << 3;      // ushort-index XOR swizzle
        ushort* sr = &swg[row * 64];
        if (which < 2) {
          const float x0 = xyz[3 * m + 0], x1 = xyz[3 * m + 1], x2 = xyz[3 * m + 2];
          const float th0 = x0 * f00 + x1 * f01 + x2 * f02;
          const float th1 = x0 * f10 + x1 * f11 + x2 * f12;
          const float s0 = sinf(th0), c0 = cosf(th0);
          const float s1 = sinf(th1), c1 = cosf(th1);
          const float v0 = acc[mf][0][r] + bsv[0];
          const float v1 = acc[mf][1][r] + bsv[1];
          const float v2 = acc[mf][2][r] + bsv[2];
          const float v3 = acc[mf][3][r] + bsv[3];
          sr[(cl)      ^ sx] = f2bs(v0 * c0 - v2 * s0);
          sr[(16 + cl) ^ sx] = f2bs(v1 * c1 - v3 * s1);
          sr[(32 + cl) ^ sx] = f2bs(v0 * s0 + v2 * c0);
          sr[(48 + cl) ^ sx] = f2bs(v1 * s1 + v3 * c1);
        } else {  // v: no rope
#pragma unroll
          for (int nf = 0; nf < 4; ++nf)
            sr[(nf * 16 + cl) ^ sx] = f2bs(acc[mf][nf][r] + bsv[nf]);
        }
      }
      asm volatile("s_waitcnt lgkmcnt(0)" ::: "memory");
      __builtin_amdgcn_sched_barrier(0);
      // ---- read phase: ds_read_b128 -> inline-asm global_store_dwordx4 ----
      {
        const int lrow = lane >> 2;                 // 0..15
        const int m = wrow + mf * 16 + lrow;
        const int a = m + 12;
        const int g96 = a / 96;
        const int rr = a - g96 * 96;
        const int orow = (g96 * 4 + (rr & 3)) * 24 + (rr >> 2);  // window-major row
#pragma unroll
        for (int inst = 0; inst < 2; ++inst) {
          const int chunk = (lane & 3) + inst * 4;  // 8-ushort group 0..7
          u32x4 v = *reinterpret_cast<const u32x4*>(
              &swg[lrow * 64 + ((chunk ^ (lrow & 7)) << 3)]);
          const ushort* p = Obf + (size_t)orow * NC + wcol + chunk * 8;
          asm volatile("global_store_dwordx4 %0, %1, off" :: "v"(p), "v"(v) : "memory");
        }
      }
      __builtin_amdgcn_sched_barrier(0);
    }
  } else {
    // f32 output: dword stores, 16-lane x 4B contiguous segments coalesce fine
#pragma unroll
    for (int mf = 0; mf < 4; ++mf)
#pragma unroll
      for (int r = 0; r < 4; ++r) {
        const int m = wrow + mf * 16 + rb + r;
        float* orow = Of + (size_t)m * NC + wcol;
#pragma unroll
        for (int nf = 0; nf < 4; ++nf) orow[nf * 16 + cl] = acc[mf][nf][r] + bsv[nf];
      }
  }
}

// ---------------- windowed attention: one wave per (window b, head h) ----------------
// qkv is window-major: row b*24+ki holds point n = g*96+dw+4*ki-12 (b=g*4+dw)
__global__ __launch_bounds__(64) void attn_win_k(const ushort* __restrict__ qkv,  // [65568][1536] bf16
                                                 const float* __restrict__ mask,  // B x 24 x 24
                                                 ushort* __restrict__ outa)       // N x 512 bf16 (point-major)
{
  __shared__ float sq[24][68];
  __shared__ float sk[24][68];
  __shared__ float sv[24][68];
  __shared__ float sS[24][25];
  const int bid = blockIdx.x;
  const int b = bid >> 3, h = bid & 7;
  const int g = b >> 2, dw = b & 3;
  const int lane  = threadIdx.x;
  const int nbase = g * 96 + dw - 12;  // + ki*4

  for (int ki = 0; ki < 24; ++ki) {
    int n = nbase + ki * 4;
    float q, k, v;
    if (n < 0) { q = k = v = -1.0f; }                 // head pad rows are -1.0
    else if (n >= N_PTS) { q = k = v = 0.0f; }        // tail pad rows are 0
    else {
      const ushort* p = qkv + (size_t)(b * 24 + ki) * 1536 + h * 64 + lane;
      q = bs2f(p[0]); k = bs2f(p[512]); v = bs2f(p[1024]);
    }
    sq[ki][lane] = q; sk[ki][lane] = k; sv[ki][lane] = v;
  }
  __syncthreads();

  for (int j = 0; j < 9; ++j) {
    int e = j * 64 + lane;
    int qi = e / 24, ki = e - qi * 24;
    float s = 0.f;
#pragma unroll
    for (int d = 0; d < 64; ++d) s = fmaf(sq[qi][d], sk[ki][d], s);
    sS[qi][ki] = s * 0.125f + mask[(size_t)b * 576 + e];
  }
  __syncthreads();

  if (lane < 24) {
    float mx = -3.4e38f;
#pragma unroll
    for (int k2 = 0; k2 < 24; ++k2) mx = fmaxf(mx, sS[lane][k2]);
    float sum = 0.f;
#pragma unroll
    for (int k2 = 0; k2 < 24; ++k2) { float t = expf(sS[lane][k2] - mx); sum += t; sS[lane][k2] = t; }
    float inv = 1.0f / sum;
#pragma unroll
    for (int k2 = 0; k2 < 24; ++k2) sS[lane][k2] *= inv;
  }
  __syncthreads();

  for (int qi = 0; qi < 24; ++qi) {
    int n = nbase + qi * 4;
    if (n < 0 || n >= N_PTS) continue;
    float o = 0.f;
#pragma unroll
    for (int ki = 0; ki < 24; ++ki) o = fmaf(sS[qi][ki], sv[ki][lane], o);
    outa[(size_t)n * 512 + h * 64 + lane] = f2bs(o);
  }
}

extern "C" void kernel_launch(void* const* d_in, const int* in_sizes, int n_in,
                              void* d_out, int out_size, void* d_ws, size_t ws_size,
                              hipStream_t stream) {
  const float* data  = (const float*)d_in[0];
  const float* xyz   = (const float*)d_in[1];
  const float* mask  = (const float*)d_in[2];
  const float* Wqkv  = (const float*)d_in[3];
  const float* bqkv  = (const float*)d_in[4];
  const float* Wproj = (const float*)d_in[5];
  const float* bproj = (const float*)d_in[6];
  const float* freqs = (const float*)d_in[7];
  float* out = (float*)d_out;

  char* ws = (char*)d_ws;
  // layout: qkv window-major 65568 rows x 1536 bf16 (201.4MB) | dat_bf / attn-out (64MB)
  //         | WqkvT (1.5MB) | WprojT (0.5MB)
  ushort* qkv_ws = (ushort*)ws;
  ushort* dat_bf = (ushort*)(ws + (size_t)201424896);
  ushort* WqkvT  = (ushort*)(ws + (size_t)268533760);
  ushort* WprojT = (ushort*)(ws + (size_t)270106624);

  cvt_data_k<<<32768, 256, 0, stream>>>(data, dat_bf);
  prep_w_k<<<1024, 256, 0, stream>>>(Wqkv, Wproj, WqkvT, WprojT);
  gemm_bt_k<1536, true><<<6144, 256, 0, stream>>>(dat_bf, WqkvT, bqkv, xyz, freqs, qkv_ws, nullptr);
  attn_win_k<<<21856, 64, 0, stream>>>(qkv_ws, mask, dat_bf);
  gemm_bt_k<512, false><<<2048, 256, 0, stream>>>(dat_bf, WprojT, bproj, nullptr, nullptr, nullptr, out);
}